// Round 10
// baseline (722.219 us; speedup 1.0000x reference)
//
#include <hip/hip_runtime.h>

// ---------------------------------------------------------------------------
// GQA + RoPE + causal attention prefill, MI355X (gfx950)
// B=2 S=2048 E=4096 HQ=32 HKV=8 D=128, SCALE = 1/64
//
// Pipeline:
//   1. prep        : ONE fused launch = convert_x + 4x tpack
//   2. gemm128     : qkv = x @ [wq|wk|wv]  (128x128 tile, 1536 blocks,
//                    launch_bounds(256,4) -> multi-block overlap)
//   3. kvpack      : K RoPE + V transpose -> packed 64-key tiles
//   4. attn        : flash causal attention v6: causal-paired q-blocks,
//                    double-buffered K/V, max-free softmax (SCALE*log2e
//                    folded into Q RoPE), MERGED QK^T (one kf ds_read
//                    feeds both q-sets' MFMAs), deferred l-sum, padded pb
//   5. gemm256     : out = attn @ wo  (256x256 tile, 256 blocks = exactly
//                    1 generation, fine-phase pipeline, counted vmcnt)
//
// Packed GEMM operand layout (per 128-row x 64-k block of 8192 elements):
//   flat = (blk128 * KB + kb) * 8192 + k2*1024 + row*8 + k1
// K tile layout (64 keys x 128 d, 8192 elem): (d>>3)*512 + s*8 + (d&7)
// V tile layout (128 d x 64 s,  8192 elem): (s>>3)*1024 + d*8 + (s&7)
// ---------------------------------------------------------------------------

typedef __bf16 bf16;
typedef __attribute__((ext_vector_type(8))) __bf16 bf16x8;
typedef __attribute__((ext_vector_type(4))) float f32x4;

#define SCLOG2E 0.02254248593737584f  /* (1/64) * log2(e) */

__device__ __forceinline__ f32x4 mfma16(bf16x8 a, bf16x8 b, f32x4 c) {
  return __builtin_amdgcn_mfma_f32_16x16x32_bf16(a, b, c, 0, 0, 0);
}

__device__ __forceinline__ void gload_lds16(const void* g, void* l) {
  __builtin_amdgcn_global_load_lds(
      (const __attribute__((address_space(1))) unsigned int*)g,
      (__attribute__((address_space(3))) unsigned int*)l, 16, 0, 0);
}

// ---------------------------------------------------------------------------
// 1. prep: fused convert_x + tpack(wq) + tpack(wk) + tpack(wv) + tpack(wo).
//    Grid 18432 blocks x 256 threads, block-uniform branch per range.
__global__ __launch_bounds__(256) void prep(const float* __restrict__ x,
                                            const float* __restrict__ wq,
                                            const float* __restrict__ wk,
                                            const float* __restrict__ wv,
                                            const float* __restrict__ wo,
                                            bf16* __restrict__ xP,
                                            bf16* __restrict__ WqkvP,
                                            bf16* __restrict__ WoP) {
  __shared__ __align__(16) float tile[64][65];
  const int bid = blockIdx.x;
  const int t = threadIdx.x;

  if (bid < 8192) {
    // --- convert_x: x (4096x4096 fp32 row-major) -> packed bf16 A ---
    int p = bid * 256 + t;
    int blk = p >> 10;
    int q = p & 1023;
    int k2 = q >> 7, row = q & 127;
    int mb = blk >> 6, kb = blk & 63;
    size_t m = (size_t)mb * 128 + row;
    size_t k = (size_t)kb * 64 + k2 * 8;
    const float* src = x + m * 4096 + k;
    float4 a = *(const float4*)(src);
    float4 b = *(const float4*)(src + 4);
    bf16x8 o;
    o[0] = (bf16)a.x; o[1] = (bf16)a.y; o[2] = (bf16)a.z; o[3] = (bf16)a.w;
    o[4] = (bf16)b.x; o[5] = (bf16)b.y; o[6] = (bf16)b.z; o[7] = (bf16)b.w;
    *(bf16x8*)(xP + (size_t)p * 8) = o;
    return;
  }

  // --- tpack: W (K=4096 x Nw fp32) -> packed bf16 B^T at n_base ---
  const float* W;
  bf16* P;
  int Nw, n_base, bx, by;
  if (bid < 12288) {
    W = wq; P = WqkvP; Nw = 4096; n_base = 0;
    int rb = bid - 8192;  bx = rb & 63; by = rb >> 6;
  } else if (bid < 13312) {
    W = wk; P = WqkvP; Nw = 1024; n_base = 4096;
    int rb = bid - 12288; bx = rb & 15; by = rb >> 4;
  } else if (bid < 14336) {
    W = wv; P = WqkvP; Nw = 1024; n_base = 5120;
    int rb = bid - 13312; bx = rb & 15; by = rb >> 4;
  } else {
    W = wo; P = WoP; Nw = 4096; n_base = 0;
    int rb = bid - 14336; bx = rb & 63; by = rb >> 6;
  }
  const int n0 = bx * 64;
  const int k0 = by * 64;
#pragma unroll
  for (int i = 0; i < 16; ++i) {
    int u = t + 256 * i;
    int kr = u >> 6, nc = u & 63;
    tile[kr][nc] = W[(size_t)(k0 + kr) * Nw + n0 + nc];
  }
  __syncthreads();
#pragma unroll
  for (int i = 0; i < 2; ++i) {
    int c = t + 256 * i;
    int k2 = c >> 6, nl = c & 63;
    int n = n_base + n0 + nl;
    bf16x8 o;
#pragma unroll
    for (int j = 0; j < 8; ++j) o[j] = (bf16)tile[k2 * 8 + j][nl];
    size_t flat = ((size_t)(n >> 7) * 64 + by) * 8192 + k2 * 1024 + (n & 127) * 8;
    *(bf16x8*)(P + flat) = o;
  }
}

// ---------------------------------------------------------------------------
// 2. gemm128: C[128mb x 128nb] = A . B^T, bf16 store (qkv GEMM).
//    256 threads / 4 waves; 32 KB LDS; launch_bounds(256,4).
__global__ __launch_bounds__(256, 4) void gemm128(const bf16* __restrict__ Ap,
                                                  const bf16* __restrict__ Bp,
                                                  bf16* __restrict__ C,
                                                  int KB, int ldC) {
  __shared__ __align__(16) bf16 lds[16384];
  const int t = threadIdx.x;
  const int w = t >> 6, lane = t & 63, q = lane >> 4, l15 = lane & 15;
  const int wm = w >> 1, wn = w & 1;
  const int mb = blockIdx.y, nb = blockIdx.x;

  f32x4 acc[4][4];
#pragma unroll
  for (int i = 0; i < 4; ++i)
#pragma unroll
    for (int j = 0; j < 4; ++j) acc[i][j] = (f32x4){0.f, 0.f, 0.f, 0.f};

  const bf16* Ab = Ap + (size_t)mb * KB * 8192;
  const bf16* Bb = Bp + (size_t)nb * KB * 8192;

  for (int kb = 0; kb < KB; ++kb) {
    __syncthreads();
    const bf16* ga = Ab + (size_t)kb * 8192;
    const bf16* gb = Bb + (size_t)kb * 8192;
#pragma unroll
    for (int i = 0; i < 4; ++i) {
      int c = w * 256 + i * 64;
      gload_lds16(ga + (size_t)(c + lane) * 8, (void*)&lds[c * 8]);
      gload_lds16(gb + (size_t)(c + lane) * 8, (void*)&lds[8192 + c * 8]);
    }
    __syncthreads();
#pragma unroll
    for (int s = 0; s < 2; ++s) {
      bf16x8 af[4], bfr[4];
#pragma unroll
      for (int i = 0; i < 4; ++i) {
        af[i] = *(const bf16x8*)&lds[(((s * 4 + q) << 7) + wm * 64 + i * 16 + l15) * 8];
        bfr[i] = *(const bf16x8*)&lds[8192 + (((s * 4 + q) << 7) + wn * 64 + i * 16 + l15) * 8];
      }
#pragma unroll
      for (int i = 0; i < 4; ++i)
#pragma unroll
        for (int j = 0; j < 4; ++j) acc[i][j] = mfma16(af[i], bfr[j], acc[i][j]);
    }
  }

  const int r0 = mb * 128 + wm * 64, c0 = nb * 128 + wn * 64;
#pragma unroll
  for (int i = 0; i < 4; ++i)
#pragma unroll
    for (int j = 0; j < 4; ++j)
#pragma unroll
      for (int r = 0; r < 4; ++r)
        C[(size_t)(r0 + i * 16 + q * 4 + r) * ldC + c0 + j * 16 + l15] =
            (bf16)acc[i][j][r];
}

// ---------------------------------------------------------------------------
// 5. gemm256: C[256 x 256] per block = A . B^T, fp32 store (out GEMM).
//    512 threads / 8 waves (2M x 4N); 128 KB LDS; fine-phase pipeline with
//    counted vmcnt; grid 256 blocks = exactly 1 generation @ 1 block/CU.
__global__ __launch_bounds__(512, 2) void gemm256(const bf16* __restrict__ Ap,
                                                  const bf16* __restrict__ Bp,
                                                  float* __restrict__ C,
                                                  int KB, int ldC) {
  __shared__ __align__(16) bf16 sA[2][16384];
  __shared__ __align__(16) bf16 sB[2][16384];
  const int t = threadIdx.x;
  const int wid = t >> 6, lane = t & 63, q = lane >> 4, l15 = lane & 15;
  const int wm = wid >> 2, wn = wid & 3;
  // XCD-bijective swizzle (gridDim.x % 8 == 0)
  const int cpx = gridDim.x >> 3;
  const int sw = (blockIdx.x & 7) * cpx + (blockIdx.x >> 3);
  const int MB = sw & 15, NB = sw >> 4;
  const int rb = (wn & 1) * 64;

  f32x4 acc[8][4];
#pragma unroll
  for (int m = 0; m < 8; ++m)
#pragma unroll
    for (int n = 0; n < 4; ++n) acc[m][n] = (f32x4){0.f, 0.f, 0.f, 0.f};

  const bf16* A0 = Ap + (size_t)(MB * 2 + 0) * KB * 8192;
  const bf16* A1 = Ap + (size_t)(MB * 2 + 1) * KB * 8192;
  const bf16* B0 = Bp + (size_t)(NB * 2 + 0) * KB * 8192;
  const bf16* B1 = Bp + (size_t)(NB * 2 + 1) * KB * 8192;

#define STAGE_REG(tc, buf, ks)                                  \
  do {                                                          \
    size_t go = (size_t)(tc)*8192 + (size_t)(ks)*4096 + t * 8;  \
    int lo = (ks)*4096 + t * 8;                                 \
    gload_lds16(A0 + go, (void*)&sA[buf][lo]);                  \
    gload_lds16(A1 + go, (void*)&sA[buf][8192 + lo]);           \
    gload_lds16(B0 + go, (void*)&sB[buf][lo]);                  \
    gload_lds16(B1 + go, (void*)&sB[buf][8192 + lo]);           \
  } while (0)

  STAGE_REG(0, 0, 0);
  STAGE_REG(0, 0, 1);
  STAGE_REG(1, 1, 0);
  asm volatile("s_waitcnt vmcnt(8)" ::: "memory");
  __builtin_amdgcn_s_barrier();

  for (int kt = 0; kt < KB; ++kt) {
    const int cur = kt & 1;
    const bf16* sAc = &sA[cur][wm * 8192];
    const bf16* sBc = &sB[cur][(wn >> 1) * 8192];
#pragma unroll
    for (int ks = 0; ks < 2; ++ks) {
      bf16x8 aF[8], bF[4];
#pragma unroll
      for (int m = 0; m < 8; ++m)
        aF[m] = *(const bf16x8*)&sAc[(ks * 4 + q) * 1024 + (m * 16 + l15) * 8];
#pragma unroll
      for (int n = 0; n < 4; ++n)
        bF[n] = *(const bf16x8*)&sBc[(ks * 4 + q) * 1024 +
                                     (rb + n * 16 + l15) * 8];

      if (ks == 0) {
        if (kt + 1 < KB) STAGE_REG(kt + 1, cur ^ 1, 1);
      } else {
        if (kt + 2 < KB) STAGE_REG(kt + 2, cur, 0);
      }

      __builtin_amdgcn_s_barrier();
      asm volatile("s_waitcnt lgkmcnt(0)" ::: "memory");
      __builtin_amdgcn_sched_barrier(0);
      __builtin_amdgcn_s_setprio(1);
#pragma unroll
      for (int m = 0; m < 8; ++m)
#pragma unroll
        for (int n = 0; n < 4; ++n) acc[m][n] = mfma16(aF[m], bF[n], acc[m][n]);
      __builtin_amdgcn_s_setprio(0);

      if (ks == 0) {
        if (kt < KB - 1) {
          asm volatile("s_waitcnt vmcnt(8)" ::: "memory");
        } else {
          asm volatile("s_waitcnt vmcnt(0)" ::: "memory");
        }
        __builtin_amdgcn_s_barrier();
      } else {
        if (kt < KB - 1) {
          if (kt == KB - 2) {
            asm volatile("s_waitcnt vmcnt(4)" ::: "memory");
          } else {
            asm volatile("s_waitcnt vmcnt(8)" ::: "memory");
          }
          __builtin_amdgcn_s_barrier();
        }
      }
    }
  }
#undef STAGE_REG

  const int r0 = MB * 256 + wm * 128, c0 = NB * 256 + wn * 64;
#pragma unroll
  for (int m = 0; m < 8; ++m)
#pragma unroll
    for (int n = 0; n < 4; ++n)
#pragma unroll
      for (int r = 0; r < 4; ++r)
        C[(size_t)(r0 + m * 16 + q * 4 + r) * ldC + c0 + n * 16 + l15] =
            acc[m][n][r];
}

// ---------------------------------------------------------------------------
// 3. kvpack: one block = one (b,kvh) x 64-key tile.
__global__ __launch_bounds__(256) void kvpack(const bf16* __restrict__ qkv,
                                              const float* __restrict__ fr,
                                              bf16* __restrict__ Kp,
                                              bf16* __restrict__ Vp) {
  __shared__ __align__(16) bf16 vt[64 * 136];
  const int t = threadIdx.x;
  const int sblk = blockIdx.x;             // 0..31
  const int bkvh = blockIdx.y;             // 0..15
  const int b = bkvh >> 3, kvh = bkvh & 7;
  const size_t tbase = ((size_t)bkvh * 32 + sblk) * 8192;
  const size_t row0 = (size_t)b * 2048 + sblk * 64;

  // --- K: rope + pack ---
#pragma unroll
  for (int it = 0; it < 4; ++it) {
    int c = it * 256 + t;                  // 0..1023
    int s_l = c >> 4, dc = c & 15;
    int s = sblk * 64 + s_l;
    bf16x8 v = *(const bf16x8*)(qkv + (row0 + s_l) * 6144 + 4096 + kvh * 128 + dc * 8);
    const float* frow = fr + (size_t)s * 128 + dc * 8;
    bf16x8 o;
#pragma unroll
    for (int p = 0; p < 4; ++p) {
      float2 cs = *(const float2*)(frow + p * 2);
      float tr = (float)v[2 * p], ti = (float)v[2 * p + 1];
      o[2 * p] = (bf16)(tr * cs.x - ti * cs.y);
      o[2 * p + 1] = (bf16)(tr * cs.y + ti * cs.x);
    }
    *(bf16x8*)(Kp + tbase + dc * 512 + s_l * 8) = o;
  }

  // --- V: load tile ---
#pragma unroll
  for (int it = 0; it < 4; ++it) {
    int c = it * 256 + t;
    int s_l = c >> 4, dc = c & 15;
    bf16x8 v = *(const bf16x8*)(qkv + (row0 + s_l) * 6144 + 5120 + kvh * 128 + dc * 8);
    *(bf16x8*)&vt[s_l * 136 + dc * 8] = v;
  }
  __syncthreads();
  // --- V: transpose + pack ---
#pragma unroll
  for (int it = 0; it < 4; ++it) {
    int c = it * 256 + t;                  // 0..1023
    int s8 = c >> 7, d = c & 127;
    bf16x8 o;
#pragma unroll
    for (int j = 0; j < 8; ++j) o[j] = vt[(s8 * 8 + j) * 136 + d];
    *(bf16x8*)(Vp + tbase + (size_t)c * 8) = o;
  }
}

// ---------------------------------------------------------------------------
// 4. flash causal attention v6 (merged QK^T, max-free softmax, deferred l).
//    grid (16 pair, 64 bh); 4 waves; wave owns 16 q-rows of q-block y AND
//    16 q-rows of q-block 31-y  -> every wave computes exactly 33 tile-units.
//    Set A is active for tiles ti <= y (w-independent -> block-uniform);
//    set B is active for ALL staged tiles. When both are active, ONE kf
//    ds_read feeds both q-sets' MFMAs (halves QK LDS traffic there) and
//    both score tiles are in flight before softmax (MFMA/VALU overlap).
//    SCALE*log2e is folded into the Q RoPE cos/sin -> softmax is a bare
//    exp2 per element.  l-sum lane-partial until one epilogue reduce.
//    pb octet stride 136 (padded, conflict-free ds_read_b128).
__global__ __launch_bounds__(256, 2) void attn_kernel(
    const bf16* __restrict__ qkv, const bf16* __restrict__ Kp,
    const bf16* __restrict__ Vp, const float* __restrict__ fr,
    bf16* __restrict__ Op) {
  __shared__ __align__(16) bf16 ktile[2][8192];
  __shared__ __align__(16) bf16 vtile[2][8192];
  __shared__ __align__(16) bf16 pb[4][1088];   // 8 octets x 136 elems (padded)

  const int t = threadIdx.x;
  const int w = t >> 6, lane = t & 63, q = lane >> 4, l15 = lane & 15;
  const int bh = blockIdx.y, b = bh >> 5, h = bh & 31, kvh = h >> 2;
  const int y = blockIdx.x;                // 0..15
  const int q0s[2] = {y * 64 + w * 16, (31 - y) * 64 + w * 16};
  const int nt = 32 - y;                   // staged 64-key tiles (set B extent)

  // --- Q fragments, RoPE fused, SCALE*log2e folded into cos/sin ---
  bf16x8 qf[2][4];
#pragma unroll
  for (int g = 0; g < 2; ++g) {
    int row = q0s[g] + l15;
    const bf16* qrow = qkv + ((size_t)(b * 2048 + row)) * 6144 + h * 128;
    const float* frow = fr + (size_t)row * 128;
#pragma unroll
    for (int tk = 0; tk < 4; ++tk) {
      bf16x8 v = *(const bf16x8*)(qrow + tk * 32 + q * 8);
      bf16x8 o;
#pragma unroll
      for (int p = 0; p < 4; ++p) {
        float2 cs = *(const float2*)(frow + (tk * 16 + q * 4 + p) * 2);
        float c = cs.x * SCLOG2E, s = cs.y * SCLOG2E;
        float tr = (float)v[2 * p], ti = (float)v[2 * p + 1];
        o[2 * p] = (bf16)(tr * c - ti * s);
        o[2 * p + 1] = (bf16)(tr * s + ti * c);
      }
      qf[g][tk] = o;
    }
  }

  f32x4 O[2][8];
#pragma unroll
  for (int g = 0; g < 2; ++g)
#pragma unroll
    for (int j = 0; j < 8; ++j) O[g][j] = (f32x4){0.f, 0.f, 0.f, 0.f};
  float lrow[2][4];                        // lane-partial until epilogue
#pragma unroll
  for (int g = 0; g < 2; ++g)
#pragma unroll
    for (int r = 0; r < 4; ++r) lrow[g][r] = 0.f;

  const bf16* Kbase = Kp + (size_t)(b * 8 + kvh) * 32 * 8192;
  const bf16* Vbase = Vp + (size_t)(b * 8 + kvh) * 32 * 8192;

  // --- prologue: stage tile 0 into buffer 0 ---
#pragma unroll
  for (int i2 = 0; i2 < 4; ++i2) {
    int c = w * 256 + i2 * 64;
    gload_lds16(Kbase + (size_t)(c + lane) * 8, (void*)&ktile[0][c * 8]);
    gload_lds16(Vbase + (size_t)(c + lane) * 8, (void*)&vtile[0][c * 8]);
  }

  int cur = 0;
  for (int ti = 0; ti < nt; ++ti) {
    __syncthreads();                       // vmcnt(0)+barrier: tile ti ready

    // issue next tile's staging NOW; latency hides under this tile's compute
    if (ti + 1 < nt) {
      const bf16* Kt = Kbase + (size_t)(ti + 1) * 8192;
      const bf16* Vt = Vbase + (size_t)(ti + 1) * 8192;
#pragma unroll
      for (int i2 = 0; i2 < 4; ++i2) {
        int c = w * 256 + i2 * 64;
        gload_lds16(Kt + (size_t)(c + lane) * 8, (void*)&ktile[cur ^ 1][c * 8]);
        gload_lds16(Vt + (size_t)(c + lane) * 8, (void*)&vtile[cur ^ 1][c * 8]);
      }
    }

    const int kb = ti * 64;
    const bf16* kt = ktile[cur];
    const bf16* vt = vtile[cur];
    const bool aAct = (ti <= y);           // block-uniform (w-independent)

    // --- QK^T: merged over active q-sets, one kf read per fragment ---
    f32x4 sc[2][4];
#pragma unroll
    for (int jn = 0; jn < 4; ++jn) {
      sc[0][jn] = (f32x4){0.f, 0.f, 0.f, 0.f};
      sc[1][jn] = (f32x4){0.f, 0.f, 0.f, 0.f};
    }
    __builtin_amdgcn_s_setprio(1);
    if (aAct) {
#pragma unroll
      for (int tk = 0; tk < 4; ++tk)
#pragma unroll
        for (int jn = 0; jn < 4; ++jn) {
          bf16x8 kf = *(const bf16x8*)&kt[(tk * 4 + q) * 512 + (jn * 16 + l15) * 8];
          sc[0][jn] = mfma16(qf[0][tk], kf, sc[0][jn]);
          sc[1][jn] = mfma16(qf[1][tk], kf, sc[1][jn]);
        }
    } else {
#pragma unroll
      for (int tk = 0; tk < 4; ++tk)
#pragma unroll
        for (int jn = 0; jn < 4; ++jn) {
          bf16x8 kf = *(const bf16x8*)&kt[(tk * 4 + q) * 512 + (jn * 16 + l15) * 8];
          sc[1][jn] = mfma16(qf[1][tk], kf, sc[1][jn]);
        }
    }
    __builtin_amdgcn_s_setprio(0);

    // --- per-set softmax + P.V ---
#pragma unroll
    for (int g = 0; g < 2; ++g) {
      if (g == 0 && !aAct) continue;       // block-uniform skip, no barriers
      const int q0 = q0s[g];
      const bool domask = (kb + 63 > q0);
#pragma unroll
      for (int r = 0; r < 4; ++r) {
        int rowq = q0 + q * 4 + r;
        float sum = 0.f;
#pragma unroll
        for (int jn = 0; jn < 4; ++jn) {
          float p = exp2f(sc[g][jn][r]);
          if (domask && (kb + jn * 16 + l15 > rowq)) p = 0.f;
          sum += p;
          pb[w][(2 * jn + (l15 >> 3)) * 136 + (q * 4 + r) * 8 + (l15 & 7)] =
              (bf16)p;
        }
        lrow[g][r] += sum;
      }

      __builtin_amdgcn_s_setprio(1);
#pragma unroll
      for (int kh = 0; kh < 2; ++kh) {
        bf16x8 a0 = *(const bf16x8*)&pb[w][(kh * 4 + q) * 136 + l15 * 8];
#pragma unroll
        for (int jn = 0; jn < 8; ++jn) {
          bf16x8 vf = *(const bf16x8*)&vt[(kh * 4 + q) * 1024 + (jn * 16 + l15) * 8];
          O[g][jn] = mfma16(a0, vf, O[g][jn]);
        }
      }
      __builtin_amdgcn_s_setprio(0);
    }
    cur ^= 1;
  }

  // --- epilogue: reduce l across l15 group, then O/l -> packed layout ---
#pragma unroll
  for (int g = 0; g < 2; ++g)
#pragma unroll
    for (int r = 0; r < 4; ++r) {
      float s = lrow[g][r];
      s += __shfl_xor(s, 1);
      s += __shfl_xor(s, 2);
      s += __shfl_xor(s, 4);
      s += __shfl_xor(s, 8);
      lrow[g][r] = s;
    }
#pragma unroll
  for (int g = 0; g < 2; ++g)
#pragma unroll
    for (int r = 0; r < 4; ++r) {
      float inv = 1.0f / lrow[g][r];
      int m = b * 2048 + q0s[g] + q * 4 + r;
#pragma unroll
      for (int jn = 0; jn < 8; ++jn) {
        int col = h * 128 + jn * 16 + l15;
        size_t flat = ((size_t)(m >> 7) * 64 + (col >> 6)) * 8192 +
                      ((col >> 3) & 7) * 1024 + (m & 127) * 8 + (col & 7);
        Op[flat] = (bf16)(O[g][jn][r] * inv);
      }
    }
}

// ---------------------------------------------------------------------------
extern "C" void kernel_launch(void* const* d_in, const int* in_sizes, int n_in,
                              void* d_out, int out_size, void* d_ws,
                              size_t ws_size, hipStream_t stream) {
  const float* x = (const float*)d_in[0];
  const float* fr = (const float*)d_in[2];
  const float* wq = (const float*)d_in[3];
  const float* wk = (const float*)d_in[4];
  const float* wv = (const float*)d_in[5];
  const float* wo = (const float*)d_in[6];
  float* out = (float*)d_out;
  char* ws = (char*)d_ws;

  bf16* xP = (bf16*)(ws);                    // 32 MB  [0, 32M)
  bf16* WqkvP = (bf16*)(ws + 33554432ull);   // 48 MB  [32M, 80M)
  bf16* WoP = (bf16*)(ws + 83886080ull);     // 32 MB  [80M, 112M)
  bf16* qkv = (bf16*)(ws + 117440512ull);    // 48 MB  [112M, 160M)
  // Kp/Vp alias WqkvP (dead after gemm1; kvpack runs after gemm1)
  bf16* Kp = (bf16*)(ws + 33554432ull);      // 8 MB
  bf16* Vp = (bf16*)(ws + 41943040ull);      // 8 MB
  bf16* attnP = xP;                          // alias: xP dead after gemm1

  prep<<<dim3(18432), dim3(256), 0, stream>>>(x, wq, wk, wv, wo, xP, WqkvP, WoP);
  gemm128<<<dim3(48, 32), dim3(256), 0, stream>>>(xP, WqkvP, qkv, 64, 6144);
  kvpack<<<dim3(32, 16), dim3(256), 0, stream>>>(qkv, fr, Kp, Vp);
  attn_kernel<<<dim3(16, 64), dim3(256), 0, stream>>>(qkv, Kp, Vp, fr, attnP);
  gemm256<<<dim3(256), dim3(512), 0, stream>>>(attnP, WoP, out, 64, 4096);
}